// Round 2
// baseline (1091.470 us; speedup 1.0000x reference)
//
#include <hip/hip_runtime.h>
#include <hip/hip_bf16.h>

typedef __attribute__((ext_vector_type(8))) short bf16x8_t;   // MFMA A/B frag (8 bf16)
typedef __attribute__((ext_vector_type(4))) float f32x4_t;    // MFMA C/D frag
typedef __attribute__((ext_vector_type(4))) float fv4;
typedef __attribute__((ext_vector_type(4))) unsigned short us4_t;
typedef __attribute__((ext_vector_type(8))) unsigned short us8_t;

// Problem constants
static constexpr int BB = 16, NN = 4096, DD = 768, HH = 16, EE = 48;

__device__ __forceinline__ unsigned short f2bf(float f) {
  unsigned int u = __float_as_uint(f);
  u += 0x7fffu + ((u >> 16) & 1u);   // RNE; inputs are finite
  return (unsigned short)(u >> 16);
}

__device__ __forceinline__ void load_lds16(const void* g, void* l) {
  __builtin_amdgcn_global_load_lds((const __attribute__((address_space(1))) void*)g,
                                   (__attribute__((address_space(3))) void*)l, 16, 0, 0);
}

// ---------------------------------------------------------------------------
// K1: cast x -> bf16, {wq,wk,wv} -> wcat bf16 [2304][768], {bq,bk,bv} -> bcat f32
// ---------------------------------------------------------------------------
__global__ __launch_bounds__(256) void cast_all(
    const float* __restrict__ x,
    const float* __restrict__ wq, const float* __restrict__ wk, const float* __restrict__ wv,
    const float* __restrict__ bq, const float* __restrict__ bk, const float* __restrict__ bv,
    unsigned short* __restrict__ xb, unsigned short* __restrict__ wcat, float* __restrict__ bcat)
{
  const long NX4 = (long)BB * NN * DD / 4;       // 12582912 float4 slots
  const long NW4 = 3L * DD * DD / 4;             // 442368
  const long NBS = 3L * DD;                      // 2304
  long stride = (long)gridDim.x * blockDim.x;
  for (long i = (long)blockIdx.x * blockDim.x + threadIdx.x; i < NX4 + NW4 + NBS; i += stride) {
    if (i < NX4) {
      fv4 v = ((const fv4*)x)[i];
      us4_t o; o.x = f2bf(v.x); o.y = f2bf(v.y); o.z = f2bf(v.z); o.w = f2bf(v.w);
      ((us4_t*)xb)[i] = o;
    } else if (i < NX4 + NW4) {
      long w = i - NX4;
      long row = (w * 4) / DD;
      long col = (w * 4) % DD;
      const float* src = (row < DD)     ? (wq + row * DD + col)
                       : (row < 2 * DD) ? (wk + (row - DD) * DD + col)
                                        : (wv + (row - 2 * DD) * DD + col);
      fv4 v = *(const fv4*)src;
      us4_t o; o.x = f2bf(v.x); o.y = f2bf(v.y); o.z = f2bf(v.z); o.w = f2bf(v.w);
      ((us4_t*)wcat)[w] = o;
    } else {
      long j = i - NX4 - NW4;
      bcat[j] = (j < DD) ? bq[j] : (j < 2 * DD) ? bk[j - DD] : bv[j - 2 * DD];
    }
  }
}

// ---------------------------------------------------------------------------
// K2/K5: bf16 GEMM, C[m][n] = sum_k A[m][k] * Bt[n][k] + bias[n]
// 128x128 tile, BK=32, 4 waves (2x2 of 64x64), m97 structure.
// OUT_BF16=1 -> bf16 store, else f32 store.
// ---------------------------------------------------------------------------
template<int OUT_BF16>
__global__ __launch_bounds__(256) void gemm_bt(
    const unsigned short* __restrict__ A, int lda, long aStride,
    const unsigned short* __restrict__ Bt, int ldb, long bStride,
    void* __restrict__ Cv, int ldc, long cStride,
    const float* __restrict__ bias, int K)
{
  __shared__ unsigned short As[128 * 32];
  __shared__ unsigned short Bs[128 * 32];
  const int zb = blockIdx.z;
  const unsigned short* Ab = A + (long)zb * aStride;
  const unsigned short* Bb = Bt + (long)zb * bStride;
  const long m0 = (long)blockIdx.x * 128;
  const int n0 = blockIdx.y * 128;
  const int t = threadIdx.x;
  const int wave = t >> 6, lane = t & 63;
  const int wr = wave >> 1, wc = wave & 1;

  f32x4_t acc[4][4] = {};

  // staging geometry: byte offset o in 8KB tile; row = o>>6 (32 bf16 = 64B rows)
  const int o0 = t * 16;
  const int row0 = o0 >> 6, kc0 = (o0 & 63) >> 1;
  const int o1 = 4096 + t * 16;
  const int row1 = o1 >> 6, kc1 = (o1 & 63) >> 1;
  unsigned short* ldsA = As + wave * 512;  // + lane*16B by HW
  unsigned short* ldsB = Bs + wave * 512;

  for (int kt = 0; kt < K; kt += 32) {
    load_lds16(Ab + (m0 + row0) * (long)lda + kt + kc0, ldsA);
    load_lds16(Ab + (m0 + row1) * (long)lda + kt + kc1, ldsA + 2048);
    load_lds16(Bb + (long)(n0 + row0) * ldb + kt + kc0, ldsB);
    load_lds16(Bb + (long)(n0 + row1) * ldb + kt + kc1, ldsB + 2048);
    __syncthreads();
    bf16x8_t af[4], bfr[4];
    const int kofs = (lane >> 4) << 3;
#pragma unroll
    for (int f = 0; f < 4; ++f) {
      af[f]  = *(const bf16x8_t*)&As[(wr * 64 + f * 16 + (lane & 15)) * 32 + kofs];
      bfr[f] = *(const bf16x8_t*)&Bs[(wc * 64 + f * 16 + (lane & 15)) * 32 + kofs];
    }
#pragma unroll
    for (int i = 0; i < 4; ++i)
#pragma unroll
      for (int j = 0; j < 4; ++j)
        acc[i][j] = __builtin_amdgcn_mfma_f32_16x16x32_bf16(af[i], bfr[j], acc[i][j], 0, 0, 0);
    __syncthreads();
  }

  // epilogue: D col = lane&15, row = (lane>>4)*4 + r  (m89-verified layout)
  const int col_l = lane & 15;
  const int rbase = (lane >> 4) << 2;
#pragma unroll
  for (int i = 0; i < 4; ++i) {
#pragma unroll
    for (int r = 0; r < 4; ++r) {
      const long grow = m0 + wr * 64 + i * 16 + rbase + r;
      if (OUT_BF16) {
        unsigned short* crow = (unsigned short*)Cv + (long)zb * cStride + grow * ldc + n0 + wc * 64;
#pragma unroll
        for (int j = 0; j < 4; ++j) {
          int col = j * 16 + col_l;
          crow[col] = f2bf(acc[i][j][r] + bias[n0 + wc * 64 + col]);
        }
      } else {
        float* crow = (float*)Cv + (long)zb * cStride + grow * ldc + n0 + wc * 64;
#pragma unroll
        for (int j = 0; j < 4; ++j) {
          int col = j * 16 + col_l;
          crow[col] = acc[i][j][r] + bias[n0 + wc * 64 + col];
        }
      }
    }
  }
}

// ---------------------------------------------------------------------------
// K3: per (b,h): G = Q_h^T K_h via MFMA (plus free diag(Q^TQ), diag(K^TK) for
// the L2 norms), then scale 1/(nq*nk), row-softmax, /tau. Writes A as bf16
// padded [48][64] (cols 48..63 zero) for the MFMA consumer in K4.
// ---------------------------------------------------------------------------
#define NCH 128
#define QSTR 136   // padded LDS stride (bf16 elems); 272B rows, 16B aligned

__global__ __launch_bounds__(256) void energy_softmax(
    const unsigned short* __restrict__ qkv, const float* __restrict__ tau_p,
    unsigned short* __restrict__ A_out)
{
  __shared__ unsigned short Qt[48 * QSTR];
  __shared__ unsigned short Kt[48 * QSTR];
  __shared__ float G_sh[48 * 49];
  __shared__ float nq2[48], nk2[48];

  const int h = blockIdx.x, b = blockIdx.y;
  const int t = threadIdx.x;
  const int wave = t >> 6, lane = t & 63;

  for (int i = t; i < 48 * 49; i += 256) G_sh[i] = 0.f;
  if (t < 48) { nq2[t] = 0.f; nk2[t] = 0.f; }

  f32x4_t accG[3][3] = {};
  f32x4_t accQ[3] = {};
  f32x4_t accK[3] = {};

  const long baseQ = (long)b * NN * 2304 + h * 48;
  const long baseK = baseQ + 768;

  // per-i staging descriptors (slot = i*256 + t)
  int s_rr[6]; long s_base[6]; int s_cg[6]; unsigned short* s_dst[6];
  for (int i = 0; i < 6; ++i) {
    int slot = i * 256 + t;
    int mat = slot / 768;
    int rr = (slot % 768) / 6;
    int cg = slot % 6;
    s_rr[i] = rr; s_cg[i] = cg;
    s_base[i] = (mat ? baseK : baseQ) + (long)cg * 8;
    s_dst[i] = mat ? Kt : Qt;
  }
  const int jstart = t & 7;
  __syncthreads();

  for (int c = 0; c < NN; c += NCH) {
    us8_t v[6];
#pragma unroll
    for (int i = 0; i < 6; ++i)
      v[i] = *(const us8_t*)(qkv + s_base[i] + (long)(c + s_rr[i]) * 2304);
#pragma unroll
    for (int i = 0; i < 6; ++i) {
      unsigned short* dst = s_dst[i];
      const int cg8 = s_cg[i] * 8, rr = s_rr[i];
#pragma unroll
      for (int jj = 0; jj < 8; ++jj) {
        int j = (jstart + jj) & 7;
        dst[(cg8 + j) * QSTR + rr] = ((const unsigned short*)&v[i])[j];
      }
    }
    __syncthreads();
    // each wave reduces its own 32-row (n) slice
    const int koff = wave * 32 + ((lane >> 4) << 3);
    bf16x8_t aq[3], ak[3];
#pragma unroll
    for (int f = 0; f < 3; ++f) {
      aq[f] = *(const bf16x8_t*)&Qt[(f * 16 + (lane & 15)) * QSTR + koff];
      ak[f] = *(const bf16x8_t*)&Kt[(f * 16 + (lane & 15)) * QSTR + koff];
    }
#pragma unroll
    for (int i = 0; i < 3; ++i) {
      accQ[i] = __builtin_amdgcn_mfma_f32_16x16x32_bf16(aq[i], aq[i], accQ[i], 0, 0, 0);
      accK[i] = __builtin_amdgcn_mfma_f32_16x16x32_bf16(ak[i], ak[i], accK[i], 0, 0, 0);
#pragma unroll
      for (int j = 0; j < 3; ++j)
        accG[i][j] = __builtin_amdgcn_mfma_f32_16x16x32_bf16(aq[i], ak[j], accG[i][j], 0, 0, 0);
    }
    __syncthreads();
  }

  // cross-wave reduce G into LDS
#pragma unroll
  for (int i = 0; i < 3; ++i)
#pragma unroll
    for (int j = 0; j < 3; ++j) {
      int e = i * 16 + ((lane >> 4) << 2);
      int qi = j * 16 + (lane & 15);
#pragma unroll
      for (int r = 0; r < 4; ++r) atomicAdd(&G_sh[(e + r) * 49 + qi], accG[i][j][r]);
    }
  // diagonal lanes contribute the sum-of-squares
  if ((lane >> 4) == ((lane & 15) >> 2)) {
    int r = (lane & 15) & 3;
#pragma unroll
    for (int f = 0; f < 3; ++f) {
      atomicAdd(&nq2[f * 16 + (lane & 15)], accQ[f][r]);
      atomicAdd(&nk2[f * 16 + (lane & 15)], accK[f][r]);
    }
  }
  __syncthreads();

  if (t < 48) {
    const float tau = *tau_p;
    const float nq = fmaxf(sqrtf(nq2[t]), 1e-12f);
    float row[48];
    float mx = -1e30f;
#pragma unroll 1
    for (int qi = 0; qi < 48; ++qi) {
      float nk = fmaxf(sqrtf(nk2[qi]), 1e-12f);
      float g = G_sh[t * 49 + qi] / (nq * nk);
      row[qi] = g; mx = fmaxf(mx, g);
    }
    float s = 0.f;
#pragma unroll 1
    for (int qi = 0; qi < 48; ++qi) { row[qi] = __expf(row[qi] - mx); s += row[qi]; }
    const float inv = 1.f / (s * tau);
    unsigned short* dst = A_out + (((long)b * HH + h) * 48) * 64 + (long)t * 64;
#pragma unroll 1
    for (int qi = 0; qi < 48; ++qi) dst[qi] = f2bf(row[qi] * inv);
#pragma unroll 1
    for (int qi = 48; qi < 64; ++qi) dst[qi] = 0;
  }
}

// ---------------------------------------------------------------------------
// K4: Btf[b][no][h*48+e] = sum_qi A_h[e][qi] * wo[no][h*48+qi]   (MFMA, K=48
// padded to 64). A-operand = wo rows (qi-contiguous), B-operand = A_h rows.
// ---------------------------------------------------------------------------
__global__ __launch_bounds__(256) void build_btf(
    const unsigned short* __restrict__ A_ws, const float* __restrict__ wo,
    unsigned short* __restrict__ btf)
{
  __shared__ unsigned short Wsh[128 * 72];
  __shared__ unsigned short Ash[48 * 72];
  const int nchunk = blockIdx.x, h = blockIdx.y, b = blockIdx.z;
  const int t = threadIdx.x;
  const int wave = t >> 6, lane = t & 63;
  const int no0 = nchunk * 128;

  for (int i = t; i < 128 * 64; i += 256) {
    int r = i >> 6, c = i & 63;
    Wsh[r * 72 + c] = (c < 48) ? f2bf(wo[(long)(no0 + r) * DD + h * 48 + c]) : (unsigned short)0;
  }
  const unsigned short* Asrc = A_ws + ((long)b * HH + h) * 48 * 64;
  for (int i = t; i < 48 * 64; i += 256) {
    int r = i >> 6, c = i & 63;
    Ash[r * 72 + c] = Asrc[r * 64 + c];   // already zero-padded in cols 48..63
  }
  __syncthreads();

  f32x4_t acc[2][3] = {};
#pragma unroll
  for (int ks = 0; ks < 2; ++ks) {
    const int k0 = ks * 32 + ((lane >> 4) << 3);
    bf16x8_t af[2], bfr[3];
#pragma unroll
    for (int mi = 0; mi < 2; ++mi)
      af[mi] = *(const bf16x8_t*)&Wsh[(wave * 32 + mi * 16 + (lane & 15)) * 72 + k0];
#pragma unroll
    for (int nj = 0; nj < 3; ++nj)
      bfr[nj] = *(const bf16x8_t*)&Ash[(nj * 16 + (lane & 15)) * 72 + k0];
#pragma unroll
    for (int mi = 0; mi < 2; ++mi)
#pragma unroll
      for (int nj = 0; nj < 3; ++nj)
        acc[mi][nj] = __builtin_amdgcn_mfma_f32_16x16x32_bf16(af[mi], bfr[nj], acc[mi][nj], 0, 0, 0);
  }

  const int col_l = lane & 15;
  const int rbase = (lane >> 4) << 2;
#pragma unroll
  for (int mi = 0; mi < 2; ++mi)
#pragma unroll
    for (int r = 0; r < 4; ++r) {
      int no = no0 + wave * 32 + mi * 16 + rbase + r;
      unsigned short* dst = btf + ((long)b * DD + no) * DD + h * 48;
#pragma unroll
      for (int nj = 0; nj < 3; ++nj)
        dst[nj * 16 + col_l] = f2bf(acc[mi][nj][r]);
    }
}

// ---------------------------------------------------------------------------
extern "C" void kernel_launch(void* const* d_in, const int* in_sizes, int n_in,
                              void* d_out, int out_size, void* d_ws, size_t ws_size,
                              hipStream_t stream)
{
  (void)in_sizes; (void)n_in; (void)out_size;
  const float* x   = (const float*)d_in[0];
  const float* wq  = (const float*)d_in[1];
  const float* bq  = (const float*)d_in[2];
  const float* wk  = (const float*)d_in[3];
  const float* bk  = (const float*)d_in[4];
  const float* wv  = (const float*)d_in[5];
  const float* bv  = (const float*)d_in[6];
  const float* wo  = (const float*)d_in[7];
  const float* bo  = (const float*)d_in[8];
  const float* tau = (const float*)d_in[9];

  char* ws = (char*)d_ws;
  // layout (bytes)
  unsigned short* xb   = (unsigned short*)(ws + 0);           // 100663296 (dead after K2)
  unsigned short* qkv  = (unsigned short*)(ws + 100663296L);  // 301989888
  unsigned short* wcat = (unsigned short*)(ws + 402653184L);  // 3538944
  float*          bcat = (float*)         (ws + 406192128L);  // 9216
  // A_ws needs B*H*48*64*2 = 1572864 B. Alias it into the xb region (xb is
  // only read by K2, which completes before K3 writes A_ws; stream-ordered,
  // deterministic across graph replays). Round-1 bug: A_ws got 393216 B at a
  // dedicated offset and overran into btf (= btf[b=0] exactly) -> b>=4 attn
  // matrices clobbered/raced by build_btf -> absmax 3.4e-3.
  unsigned short* A_ws = (unsigned short*)(ws + 0);
  unsigned short* btf  = (unsigned short*)(ws + 406594560L);  // 18874368, ends 425468928
  if (ws_size < 425468928ULL) return;  // fails validation loudly rather than corrupting

  cast_all<<<2048, 256, 0, stream>>>(x, wq, wk, wv, bq, bk, bv, xb, wcat, bcat);

  // QKV: [65536 x 2304] = xb [65536 x 768] * wcat^T, +bcat, bf16 out
  gemm_bt<1><<<dim3(512, 18, 1), 256, 0, stream>>>(
      xb, DD, 0L, wcat, DD, 0L, qkv, 2304, 0L, bcat, DD);

  energy_softmax<<<dim3(HH, BB, 1), 256, 0, stream>>>(qkv, tau, A_ws);

  build_btf<<<dim3(6, HH, BB), 256, 0, stream>>>(A_ws, wo, btf);

  // out[b] = V[b] [4096x768] * Btf[b]^T + bo, f32 out
  gemm_bt<0><<<dim3(32, 6, BB), 256, 0, stream>>>(
      qkv + 1536, 2304, (long)NN * 2304, btf, DD, (long)DD * DD,
      d_out, DD, (long)NN * DD, bo, DD);
}